// Round 9
// baseline (386.222 us; speedup 1.0000x reference)
//
#include <hip/hip_runtime.h>
#include <hip/hip_fp16.h>

// RepulsionNLH: erep_atomic[a] = 0.5*BOHR * sum_{e: src[e]==a} Z[src]*Z[dst]*phi(e)*switch[e]/dist[e]
// phi(e) = sum_k CS[s12][k] * exp(-ALPHAS[s12][k] * dist[e]),  s12 = species[src] + 92*species[dst]
//
// R9: p1 was latency-bound on a 2-level gather chain with waves*MLP stuck ~48.
//  (a) k1_s12: dedicated max-occupancy kernel pre-gathers species -> u16 s12'
//      (93-stride, collision-free), removing 12.8M u8 gathers from p1.
//  (b) Z premultiplied into a 93-stride f16 table copy (legal only on the
//      93-stride copy: the reference's 92-stride index collides).
//  (c) p2a/p2b fused: one block per bucket, ds_add_f32 into LDS, direct out.
//  (d) p1 single-group pipeline (VGPR down), wave-scan, multi-wave copy-out.

#define ZMAX_C 92
#define TAB93  93
#define NTAB   (TAB93 * TAB93)   // 8649
#define HALF_BOHR 0.264588605f   // 0.5 * 0.52917721
#define NBMAX 64
#define APB 2048                 // atoms per bucket
#define APB_LOG 11
#define TPB 256
#define EPT 16                   // edges per thread in p1
#define BLK_EDGES (TPB * EPT)    // 4096
#define K1_EPT 8
#define K1_BLK (TPB * K1_EPT)    // 2048

typedef int            ivec4 __attribute__((ext_vector_type(4)));
typedef float          fvec4 __attribute__((ext_vector_type(4)));
typedef unsigned short usvec4 __attribute__((ext_vector_type(4)));

#if __has_builtin(__builtin_amdgcn_rcpf)
#define FAST_RCP(x) __builtin_amdgcn_rcpf(x)
#else
#define FAST_RCP(x) (1.0f / (x))
#endif

// ---------------- p0: build Z-premult f16 table (93-stride), spc8, cursors --
__global__ __launch_bounds__(TPB) void p0_prep(
    const float* __restrict__ CS, const float* __restrict__ ALPHAS,
    const int* __restrict__ species,
    uint4* __restrict__ tab16, unsigned char* __restrict__ spc8,
    unsigned* __restrict__ cursor, int n_atoms, int nb)
{
    int i = blockIdx.x * TPB + threadIdx.x;
    if (i < NTAB) {
        int sd = i / TAB93;
        int ss = i - TAB93 * sd;
        int ref = ss + ZMAX_C * sd;          // reference's (colliding) index
        float Z = (ss > 0 && sd > 0) ? (float)(ss * sd) : 0.0f;
        __half h[8];
        h[0] = __float2half_rn(CS[3*ref+0] * Z);
        h[1] = __float2half_rn(CS[3*ref+1] * Z);
        h[2] = __float2half_rn(CS[3*ref+2] * Z);
        h[3] = __float2half_rn(-ALPHAS[3*ref+0]);
        h[4] = __float2half_rn(-ALPHAS[3*ref+1]);
        h[5] = __float2half_rn(-ALPHAS[3*ref+2]);
        h[6] = __half(0.0f); h[7] = __half(0.0f);
        tab16[i] = *reinterpret_cast<uint4*>(h);
    }
    if (i < n_atoms) spc8[i] = (unsigned char)species[i];
    if (i < nb) cursor[i] = 0u;
}

__device__ __forceinline__ float half_lo(unsigned u) {
    return __half2float(*reinterpret_cast<const __half*>(&u));
}
__device__ __forceinline__ float half_hi(unsigned u) {
    unsigned s = u >> 16;
    return __half2float(*reinterpret_cast<const __half*>(&s));
}

// ---------------- k1: pre-gather species -> u16 s12' (93-stride) ------------
__global__ __launch_bounds__(TPB) void k1_s12(
    const int* __restrict__ edge_src, const int* __restrict__ edge_dst,
    const unsigned char* __restrict__ spc8,
    unsigned short* __restrict__ s12out, int n_edges)
{
    int tid = threadIdx.x;
    int lane = tid & 63, wave = tid >> 6;
    long long wbase = (long long)blockIdx.x * K1_BLK + (long long)wave * (64 * K1_EPT);
    long long eA = wbase + lane * 4;
    long long eB = eA + 256;

    if (eB + 3 < (long long)n_edges) {
        ivec4 sA = __builtin_nontemporal_load((const ivec4*)(edge_src + eA));
        ivec4 dA = __builtin_nontemporal_load((const ivec4*)(edge_dst + eA));
        ivec4 sB = __builtin_nontemporal_load((const ivec4*)(edge_src + eB));
        ivec4 dB = __builtin_nontemporal_load((const ivec4*)(edge_dst + eB));
        int ssA[4], sdA[4], ssB[4], sdB[4];
        #pragma unroll
        for (int k = 0; k < 4; ++k) { ssA[k] = spc8[sA[k]]; sdA[k] = spc8[dA[k]]; }
        #pragma unroll
        for (int k = 0; k < 4; ++k) { ssB[k] = spc8[sB[k]]; sdB[k] = spc8[dB[k]]; }
        usvec4 oA, oB;
        #pragma unroll
        for (int k = 0; k < 4; ++k) {
            oA[k] = (unsigned short)(ssA[k] + TAB93 * sdA[k]);
            oB[k] = (unsigned short)(ssB[k] + TAB93 * sdB[k]);
        }
        *(usvec4*)(s12out + eA) = oA;
        *(usvec4*)(s12out + eB) = oB;
    } else {
        #pragma unroll
        for (int g = 0; g < 2; ++g) {
            long long e0 = g ? eB : eA;
            for (int k = 0; k < 4; ++k) {
                long long e = e0 + k;
                if (e < (long long)n_edges) {
                    int ss = spc8[edge_src[e]], sd = spc8[edge_dst[e]];
                    s12out[e] = (unsigned short)(ss + TAB93 * sd);
                }
            }
        }
    }
}

// ---------------- p1: compute + bin ----------------
__global__ __launch_bounds__(TPB) void p1_bin(
    const int* __restrict__ edge_src,
    const unsigned short* __restrict__ s12arr,
    const float* __restrict__ dist, const float* __restrict__ swt,
    const uint4* __restrict__ tab16,
    unsigned* __restrict__ pairs, unsigned* __restrict__ cursor,
    int nb, int cap, int n_edges)
{
    __shared__ unsigned stage[BLK_EDGES];   // 16 KB: packed {lsrc<<16 | f16}
    __shared__ unsigned hist[NBMAX];
    __shared__ unsigned lbase[NBMAX];
    __shared__ unsigned gbase[NBMAX];

    int tid = threadIdx.x;
    if (tid < NBMAX) hist[tid] = 0;
    __syncthreads();

    int lane = tid & 63, wave = tid >> 6;
    long long wbase = (long long)blockIdx.x * BLK_EDGES + (long long)wave * (64 * EPT);

    unsigned meta[EPT];   // bit31 valid | rank<<17 | b<<11 | lsrc
    float    vals[EPT];

    for (int j = 0; j < EPT / 4; ++j) {
        long long e0 = wbase + j * 256 + lane * 4;
        int src[4]; int s12[4]; float r[4], w[4]; bool valid4;
        if (e0 + 3 < (long long)n_edges) {
            ivec4  s4 = __builtin_nontemporal_load((const ivec4*) (edge_src + e0));
            usvec4 i4 = __builtin_nontemporal_load((const usvec4*)(s12arr + e0));
            fvec4  r4 = __builtin_nontemporal_load((const fvec4*) (dist + e0));
            fvec4  w4 = __builtin_nontemporal_load((const fvec4*) (swt + e0));
            #pragma unroll
            for (int k = 0; k < 4; ++k) {
                src[k] = s4[k]; s12[k] = i4[k]; r[k] = r4[k]; w[k] = w4[k];
            }
            valid4 = true;
        } else {
            #pragma unroll
            for (int k = 0; k < 4; ++k) {
                long long e = e0 + k;
                bool v = (e < (long long)n_edges);
                src[k] = v ? edge_src[e] : 0;
                s12[k] = v ? (int)s12arr[e] : 0;
                r[k]   = v ? dist[e] : 1.f;
                w[k]   = v ? swt[e]  : 0.f;
            }
            valid4 = false;
        }
        // all 4 table gathers in flight (single 16 B dwordx4 each)
        uint4 t[4];
        #pragma unroll
        for (int k = 0; k < 4; ++k) t[k] = tab16[s12[k]];
        // compute + bin
        #pragma unroll
        for (int k = 0; k < 4; ++k) {
            int idx = j * 4 + k;
            meta[idx] = 0u; vals[idx] = 0.f;
            bool valid = valid4 || (e0 + k < (long long)n_edges);
            if (valid) {
                float c0 = half_lo(t[k].x), c1 = half_hi(t[k].x);
                float c2 = half_lo(t[k].y), na0 = half_hi(t[k].y);
                float na1 = half_lo(t[k].z), na2 = half_hi(t[k].z);
                float phi = c0 * __expf(na0 * r[k])
                          + c1 * __expf(na1 * r[k])
                          + c2 * __expf(na2 * r[k]);
                float val = HALF_BOHR * phi * w[k] * FAST_RCP(r[k]);  // Z premult in c
                unsigned b    = (unsigned)src[k] >> APB_LOG;
                unsigned lsrc = (unsigned)src[k] & (APB - 1);
                unsigned rank = atomicAdd(&hist[b], 1u);   // < 4096
                meta[idx] = 0x80000000u | (rank << 17) | (b << 11) | lsrc;
                vals[idx] = val;
            }
        }
    }
    __syncthreads();
    // wave-parallel exclusive scan of bucket counts (lanes 0..63 of wave 0)
    if (tid < 64) {
        unsigned v = (tid < nb) ? hist[tid] : 0u;
        unsigned x = v;
        #pragma unroll
        for (int off = 1; off < 64; off <<= 1) {
            unsigned y = __shfl_up(x, off);
            if ((tid & 63) >= off) x += y;
        }
        if (tid < nb) lbase[tid] = x - v;
    }
    __syncthreads();
    if (tid < nb) {
        unsigned c = hist[tid];
        gbase[tid] = c ? atomicAdd(cursor + tid, c) : 0u;
    }
    __syncthreads();
    #pragma unroll
    for (int idx = 0; idx < EPT; ++idx) {
        unsigned m = meta[idx];
        if (!(m & 0x80000000u)) continue;
        unsigned pos = lbase[(m >> 11) & 63u] + ((m >> 17) & 0x3FFFu);
        unsigned lsrc = m & (APB - 1);
        unsigned short hb = __half_as_ushort(__float2half_rn(vals[idx]));
        stage[pos] = (lsrc << 16) | (unsigned)hb;
    }
    __syncthreads();
    // coalesced copy-out, buckets distributed across the 4 waves
    for (int b = wave; b < nb; b += 4) {
        unsigned cnt = hist[b], lb = lbase[b], gb = gbase[b];
        unsigned* dst = pairs + (size_t)b * (size_t)cap + gb;
        for (unsigned i = lane; i < cnt; i += 64)
            if (gb + i < (unsigned)cap) dst[i] = stage[lb + i];
    }
}

// ---------------- p2: per-bucket LDS accumulation -> out (fused) ------------
__global__ __launch_bounds__(1024) void p2_out(
    const unsigned* __restrict__ pairs, const unsigned* __restrict__ cursor,
    float* __restrict__ out, int cap, int n_atoms)
{
    int b = blockIdx.x;
    __shared__ float acc[APB];
    for (int i = threadIdx.x; i < APB; i += 1024) acc[i] = 0.f;
    __syncthreads();
    unsigned cnt = cursor[b];
    if (cnt > (unsigned)cap) cnt = (unsigned)cap;
    const unsigned* p = pairs + (size_t)b * (size_t)cap;
    unsigned i = threadIdx.x;
    for (; i + 3u * 1024u < cnt; i += 4u * 1024u) {
        unsigned v0 = p[i], v1 = p[i + 1024u], v2 = p[i + 2048u], v3 = p[i + 3072u];
        unsafeAtomicAdd(&acc[v0 >> 16], __half2float(__ushort_as_half((unsigned short)(v0 & 0xFFFFu))));
        unsafeAtomicAdd(&acc[v1 >> 16], __half2float(__ushort_as_half((unsigned short)(v1 & 0xFFFFu))));
        unsafeAtomicAdd(&acc[v2 >> 16], __half2float(__ushort_as_half((unsigned short)(v2 & 0xFFFFu))));
        unsafeAtomicAdd(&acc[v3 >> 16], __half2float(__ushort_as_half((unsigned short)(v3 & 0xFFFFu))));
    }
    for (; i < cnt; i += 1024u) {
        unsigned v = p[i];
        unsafeAtomicAdd(&acc[v >> 16], __half2float(__ushort_as_half((unsigned short)(v & 0xFFFFu))));
    }
    __syncthreads();
    int base = b * APB;
    int lim  = n_atoms - base;           // <= APB for last bucket
    if (lim > APB) lim = APB;
    for (int k = threadIdx.x; k < lim; k += 1024) out[base + k] = acc[k];
}

// ---------------- fallback: direct device atomics ----------------
__global__ __launch_bounds__(TPB) void erep_edges_direct(
    const int* __restrict__ edge_src, const int* __restrict__ edge_dst,
    const float* __restrict__ dist, const float* __restrict__ swt,
    const int* __restrict__ species, const float* __restrict__ CS,
    const float* __restrict__ ALPHAS, float* __restrict__ out, int n_edges)
{
    int e = blockIdx.x * TPB + threadIdx.x;
    if (e >= n_edges) return;
    int ss = species[edge_src[e]], sd = species[edge_dst[e]];
    int prod = ss * sd;
    if (prod == 0) return;
    int s12 = ss + ZMAX_C * sd;
    float r = dist[e];
    float phi = CS[3*s12+0] * __expf(-ALPHAS[3*s12+0] * r)
              + CS[3*s12+1] * __expf(-ALPHAS[3*s12+1] * r)
              + CS[3*s12+2] * __expf(-ALPHAS[3*s12+2] * r);
    atomicAdd(out + edge_src[e],
              HALF_BOHR * (float)prod * phi * swt[e] * FAST_RCP(r));
}

extern "C" void kernel_launch(void* const* d_in, const int* in_sizes, int n_in,
                              void* d_out, int out_size, void* d_ws, size_t ws_size,
                              hipStream_t stream)
{
    const int*   species  = (const int*)  d_in[0];
    const int*   edge_src = (const int*)  d_in[1];
    const int*   edge_dst = (const int*)  d_in[2];
    const float* dist     = (const float*)d_in[3];
    const float* swt      = (const float*)d_in[4];
    const float* CS       = (const float*)d_in[5];
    const float* ALPHAS   = (const float*)d_in[6];
    float* out = (float*)d_out;

    int n_atoms = in_sizes[0];
    int n_edges = in_sizes[1];

    int nb = (n_atoms + APB - 1) / APB;
    long long capll = (long long)n_edges / nb + (long long)n_edges / ((long long)nb * 32) + 256;
    int cap = (int)((capll + 31) & ~31LL);

    size_t pairs_sz = ((size_t)nb * (size_t)cap * 4 + 255) & ~(size_t)255;
    size_t cur_sz   = ((size_t)nb * 4 + 255) & ~(size_t)255;
    size_t tab_sz   = ((size_t)NTAB * 16 + 255) & ~(size_t)255;
    size_t spc_sz   = ((size_t)n_atoms + 255) & ~(size_t)255;
    size_t s12_sz   = ((size_t)n_edges * 2 + 255) & ~(size_t)255;
    size_t need = pairs_sz + cur_sz + tab_sz + spc_sz + s12_sz;

    if (nb <= NBMAX && n_edges > 0 && ws_size >= need) {
        char* w = (char*)d_ws;
        unsigned*       pairs  = (unsigned*)w;
        unsigned*       cursor = (unsigned*)(w + pairs_sz);
        uint4*          tab16  = (uint4*)(w + pairs_sz + cur_sz);
        unsigned char*  spc8   = (unsigned char*)(w + pairs_sz + cur_sz + tab_sz);
        unsigned short* s12arr = (unsigned short*)(w + pairs_sz + cur_sz + tab_sz + spc_sz);

        int pmax = n_atoms > NTAB ? n_atoms : NTAB;
        p0_prep<<<(pmax + TPB - 1) / TPB, TPB, 0, stream>>>(
            CS, ALPHAS, species, tab16, spc8, cursor, n_atoms, nb);

        k1_s12<<<(n_edges + K1_BLK - 1) / K1_BLK, TPB, 0, stream>>>(
            edge_src, edge_dst, spc8, s12arr, n_edges);

        p1_bin<<<(n_edges + BLK_EDGES - 1) / BLK_EDGES, TPB, 0, stream>>>(
            edge_src, s12arr, dist, swt, tab16, pairs, cursor, nb, cap, n_edges);

        p2_out<<<nb, 1024, 0, stream>>>(pairs, cursor, out, cap, n_atoms);
    } else {
        (void)hipMemsetAsync(d_out, 0, (size_t)out_size * sizeof(float), stream);
        erep_edges_direct<<<(n_edges + TPB - 1) / TPB, TPB, 0, stream>>>(
            edge_src, edge_dst, dist, swt, species, CS, ALPHAS, out, n_edges);
    }
}

// Round 10
// 263.308 us; speedup vs baseline: 1.4668x; 1.4668x over previous
//
#include <hip/hip_runtime.h>
#include <hip/hip_fp16.h>

// RepulsionNLH: erep_atomic[a] = 0.5*BOHR * sum_{e: src[e]==a} Z[src]*Z[dst]*phi(e)*switch[e]/dist[e]
// phi(e) = sum_k CS[s12][k] * exp(-ALPHAS[s12][k] * dist[e]),  s12 = species[src] + 92*species[dst]
//
// R10: R9's fused p2 (1 block/bucket = 49 blocks) was LDS-atomic serialized at
// ~3.1 cyc/pair on only 49 CUs -> 168 us. Restore SPLITS=16 partials (784
// blocks => ~31 us LDS-atomic floor across 256 CUs). Front-end (k1 s12
// pre-gather + Z-premult 93-stride f16 table) kept from R9.

#define ZMAX_C 92
#define TAB93  93
#define NTAB   (TAB93 * TAB93)   // 8649
#define HALF_BOHR 0.264588605f   // 0.5 * 0.52917721
#define NBMAX 64
#define APB 2048                 // atoms per bucket
#define APB_LOG 11
#define SPLITS 16
#define TPB 256
#define EPT 16                   // edges per thread in p1
#define BLK_EDGES (TPB * EPT)    // 4096
#define K1_EPT 8
#define K1_BLK (TPB * K1_EPT)    // 2048

typedef int            ivec4 __attribute__((ext_vector_type(4)));
typedef float          fvec4 __attribute__((ext_vector_type(4)));
typedef unsigned short usvec4 __attribute__((ext_vector_type(4)));

#if __has_builtin(__builtin_amdgcn_rcpf)
#define FAST_RCP(x) __builtin_amdgcn_rcpf(x)
#else
#define FAST_RCP(x) (1.0f / (x))
#endif

// ---------------- p0: build Z-premult f16 table (93-stride), spc8, cursors --
__global__ __launch_bounds__(TPB) void p0_prep(
    const float* __restrict__ CS, const float* __restrict__ ALPHAS,
    const int* __restrict__ species,
    uint4* __restrict__ tab16, unsigned char* __restrict__ spc8,
    unsigned* __restrict__ cursor, int n_atoms, int nb)
{
    int i = blockIdx.x * TPB + threadIdx.x;
    if (i < NTAB) {
        int sd = i / TAB93;
        int ss = i - TAB93 * sd;
        int ref = ss + ZMAX_C * sd;          // reference's (colliding) index
        float Z = (ss > 0 && sd > 0) ? (float)(ss * sd) : 0.0f;
        __half h[8];
        h[0] = __float2half_rn(CS[3*ref+0] * Z);
        h[1] = __float2half_rn(CS[3*ref+1] * Z);
        h[2] = __float2half_rn(CS[3*ref+2] * Z);
        h[3] = __float2half_rn(-ALPHAS[3*ref+0]);
        h[4] = __float2half_rn(-ALPHAS[3*ref+1]);
        h[5] = __float2half_rn(-ALPHAS[3*ref+2]);
        h[6] = __half(0.0f); h[7] = __half(0.0f);
        tab16[i] = *reinterpret_cast<uint4*>(h);
    }
    if (i < n_atoms) spc8[i] = (unsigned char)species[i];
    if (i < nb) cursor[i] = 0u;
}

__device__ __forceinline__ float half_lo(unsigned u) {
    return __half2float(*reinterpret_cast<const __half*>(&u));
}
__device__ __forceinline__ float half_hi(unsigned u) {
    unsigned s = u >> 16;
    return __half2float(*reinterpret_cast<const __half*>(&s));
}

// ---------------- k1: pre-gather species -> u16 s12' (93-stride) ------------
__global__ __launch_bounds__(TPB) void k1_s12(
    const int* __restrict__ edge_src, const int* __restrict__ edge_dst,
    const unsigned char* __restrict__ spc8,
    unsigned short* __restrict__ s12out, int n_edges)
{
    int tid = threadIdx.x;
    int lane = tid & 63, wave = tid >> 6;
    long long wbase = (long long)blockIdx.x * K1_BLK + (long long)wave * (64 * K1_EPT);
    long long eA = wbase + lane * 4;
    long long eB = eA + 256;

    if (eB + 3 < (long long)n_edges) {
        ivec4 sA = __builtin_nontemporal_load((const ivec4*)(edge_src + eA));
        ivec4 dA = __builtin_nontemporal_load((const ivec4*)(edge_dst + eA));
        ivec4 sB = __builtin_nontemporal_load((const ivec4*)(edge_src + eB));
        ivec4 dB = __builtin_nontemporal_load((const ivec4*)(edge_dst + eB));
        int ssA[4], sdA[4], ssB[4], sdB[4];
        #pragma unroll
        for (int k = 0; k < 4; ++k) { ssA[k] = spc8[sA[k]]; sdA[k] = spc8[dA[k]]; }
        #pragma unroll
        for (int k = 0; k < 4; ++k) { ssB[k] = spc8[sB[k]]; sdB[k] = spc8[dB[k]]; }
        usvec4 oA, oB;
        #pragma unroll
        for (int k = 0; k < 4; ++k) {
            oA[k] = (unsigned short)(ssA[k] + TAB93 * sdA[k]);
            oB[k] = (unsigned short)(ssB[k] + TAB93 * sdB[k]);
        }
        *(usvec4*)(s12out + eA) = oA;
        *(usvec4*)(s12out + eB) = oB;
    } else {
        #pragma unroll
        for (int g = 0; g < 2; ++g) {
            long long e0 = g ? eB : eA;
            for (int k = 0; k < 4; ++k) {
                long long e = e0 + k;
                if (e < (long long)n_edges) {
                    int ss = spc8[edge_src[e]], sd = spc8[edge_dst[e]];
                    s12out[e] = (unsigned short)(ss + TAB93 * sd);
                }
            }
        }
    }
}

// ---------------- p1: compute + bin ----------------
__global__ __launch_bounds__(TPB) void p1_bin(
    const int* __restrict__ edge_src,
    const unsigned short* __restrict__ s12arr,
    const float* __restrict__ dist, const float* __restrict__ swt,
    const uint4* __restrict__ tab16,
    unsigned* __restrict__ pairs, unsigned* __restrict__ cursor,
    int nb, int cap, int n_edges)
{
    __shared__ unsigned stage[BLK_EDGES];   // 16 KB: packed {lsrc<<16 | f16}
    __shared__ unsigned hist[NBMAX];
    __shared__ unsigned lbase[NBMAX];
    __shared__ unsigned gbase[NBMAX];

    int tid = threadIdx.x;
    if (tid < NBMAX) hist[tid] = 0;
    __syncthreads();

    int lane = tid & 63, wave = tid >> 6;
    long long wbase = (long long)blockIdx.x * BLK_EDGES + (long long)wave * (64 * EPT);

    unsigned meta[EPT];   // bit31 valid | rank<<17 | b<<11 | lsrc
    float    vals[EPT];

    for (int j = 0; j < EPT / 4; ++j) {
        long long e0 = wbase + j * 256 + lane * 4;
        int src[4]; int s12[4]; float r[4], w[4]; bool valid4;
        if (e0 + 3 < (long long)n_edges) {
            ivec4  s4 = __builtin_nontemporal_load((const ivec4*) (edge_src + e0));
            usvec4 i4 = __builtin_nontemporal_load((const usvec4*)(s12arr + e0));
            fvec4  r4 = __builtin_nontemporal_load((const fvec4*) (dist + e0));
            fvec4  w4 = __builtin_nontemporal_load((const fvec4*) (swt + e0));
            #pragma unroll
            for (int k = 0; k < 4; ++k) {
                src[k] = s4[k]; s12[k] = i4[k]; r[k] = r4[k]; w[k] = w4[k];
            }
            valid4 = true;
        } else {
            #pragma unroll
            for (int k = 0; k < 4; ++k) {
                long long e = e0 + k;
                bool v = (e < (long long)n_edges);
                src[k] = v ? edge_src[e] : 0;
                s12[k] = v ? (int)s12arr[e] : 0;
                r[k]   = v ? dist[e] : 1.f;
                w[k]   = v ? swt[e]  : 0.f;
            }
            valid4 = false;
        }
        // all 4 table gathers in flight (single 16 B dwordx4 each)
        uint4 t[4];
        #pragma unroll
        for (int k = 0; k < 4; ++k) t[k] = tab16[s12[k]];
        // compute + bin
        #pragma unroll
        for (int k = 0; k < 4; ++k) {
            int idx = j * 4 + k;
            meta[idx] = 0u; vals[idx] = 0.f;
            bool valid = valid4 || (e0 + k < (long long)n_edges);
            if (valid) {
                float c0 = half_lo(t[k].x), c1 = half_hi(t[k].x);
                float c2 = half_lo(t[k].y), na0 = half_hi(t[k].y);
                float na1 = half_lo(t[k].z), na2 = half_hi(t[k].z);
                float phi = c0 * __expf(na0 * r[k])
                          + c1 * __expf(na1 * r[k])
                          + c2 * __expf(na2 * r[k]);
                float val = HALF_BOHR * phi * w[k] * FAST_RCP(r[k]);  // Z premult in c
                unsigned b    = (unsigned)src[k] >> APB_LOG;
                unsigned lsrc = (unsigned)src[k] & (APB - 1);
                unsigned rank = atomicAdd(&hist[b], 1u);   // < 4096
                meta[idx] = 0x80000000u | (rank << 17) | (b << 11) | lsrc;
                vals[idx] = val;
            }
        }
    }
    __syncthreads();
    // wave-parallel exclusive scan of bucket counts (lanes 0..63 of wave 0)
    if (tid < 64) {
        unsigned v = (tid < nb) ? hist[tid] : 0u;
        unsigned x = v;
        #pragma unroll
        for (int off = 1; off < 64; off <<= 1) {
            unsigned y = __shfl_up(x, off);
            if ((tid & 63) >= off) x += y;
        }
        if (tid < nb) lbase[tid] = x - v;
    }
    __syncthreads();
    if (tid < nb) {
        unsigned c = hist[tid];
        gbase[tid] = c ? atomicAdd(cursor + tid, c) : 0u;
    }
    __syncthreads();
    #pragma unroll
    for (int idx = 0; idx < EPT; ++idx) {
        unsigned m = meta[idx];
        if (!(m & 0x80000000u)) continue;
        unsigned pos = lbase[(m >> 11) & 63u] + ((m >> 17) & 0x3FFFu);
        unsigned lsrc = m & (APB - 1);
        unsigned short hb = __half_as_ushort(__float2half_rn(vals[idx]));
        stage[pos] = (lsrc << 16) | (unsigned)hb;
    }
    __syncthreads();
    // coalesced copy-out, buckets distributed across the 4 waves
    for (int b = wave; b < nb; b += 4) {
        unsigned cnt = hist[b], lb = lbase[b], gb = gbase[b];
        unsigned* dst = pairs + (size_t)b * (size_t)cap + gb;
        for (unsigned i = lane; i < cnt; i += 64)
            if (gb + i < (unsigned)cap) dst[i] = stage[lb + i];
    }
}

// ---------------- p2a: per-bucket-slice LDS accumulation ----------------
__global__ __launch_bounds__(TPB) void p2a_reduce(
    const unsigned* __restrict__ pairs, const unsigned* __restrict__ cursor,
    float* __restrict__ partial, int cap, int stride)
{
    int b = blockIdx.x / SPLITS;
    int s = blockIdx.x % SPLITS;
    __shared__ float acc[APB];
    for (int i = threadIdx.x; i < APB; i += TPB) acc[i] = 0.f;
    __syncthreads();
    unsigned cnt = cursor[b];
    if (cnt > (unsigned)cap) cnt = (unsigned)cap;
    unsigned beg = (unsigned)((unsigned long long)cnt * s / SPLITS);
    unsigned end = (unsigned)((unsigned long long)cnt * (s + 1) / SPLITS);
    const unsigned* p = pairs + (size_t)b * (size_t)cap;
    unsigned i = beg + threadIdx.x;
    for (; i + 3u * TPB < end; i += 4u * TPB) {
        unsigned v0 = p[i], v1 = p[i + TPB], v2 = p[i + 2u*TPB], v3 = p[i + 3u*TPB];
        unsafeAtomicAdd(&acc[v0 >> 16], __half2float(__ushort_as_half((unsigned short)(v0 & 0xFFFFu))));
        unsafeAtomicAdd(&acc[v1 >> 16], __half2float(__ushort_as_half((unsigned short)(v1 & 0xFFFFu))));
        unsafeAtomicAdd(&acc[v2 >> 16], __half2float(__ushort_as_half((unsigned short)(v2 & 0xFFFFu))));
        unsafeAtomicAdd(&acc[v3 >> 16], __half2float(__ushort_as_half((unsigned short)(v3 & 0xFFFFu))));
    }
    for (; i < end; i += TPB) {
        unsigned v = p[i];
        unsafeAtomicAdd(&acc[v >> 16], __half2float(__ushort_as_half((unsigned short)(v & 0xFFFFu))));
    }
    __syncthreads();
    float* prow = partial + (size_t)s * stride + (size_t)b * APB;
    for (int k = threadIdx.x; k < APB; k += TPB) prow[k] = acc[k];
}

// ---------------- p2b: sum partials -> out ----------------
__global__ __launch_bounds__(TPB) void p2b_sum(
    const float* __restrict__ partial, float* __restrict__ out, int n, int stride)
{
    int i = blockIdx.x * TPB + threadIdx.x;
    if (i >= n) return;
    float s = 0.f;
    #pragma unroll
    for (int x = 0; x < SPLITS; ++x) s += partial[(size_t)x * stride + i];
    out[i] = s;
}

// ---------------- fallback: direct device atomics ----------------
__global__ __launch_bounds__(TPB) void erep_edges_direct(
    const int* __restrict__ edge_src, const int* __restrict__ edge_dst,
    const float* __restrict__ dist, const float* __restrict__ swt,
    const int* __restrict__ species, const float* __restrict__ CS,
    const float* __restrict__ ALPHAS, float* __restrict__ out, int n_edges)
{
    int e = blockIdx.x * TPB + threadIdx.x;
    if (e >= n_edges) return;
    int ss = species[edge_src[e]], sd = species[edge_dst[e]];
    int prod = ss * sd;
    if (prod == 0) return;
    int s12 = ss + ZMAX_C * sd;
    float r = dist[e];
    float phi = CS[3*s12+0] * __expf(-ALPHAS[3*s12+0] * r)
              + CS[3*s12+1] * __expf(-ALPHAS[3*s12+1] * r)
              + CS[3*s12+2] * __expf(-ALPHAS[3*s12+2] * r);
    atomicAdd(out + edge_src[e],
              HALF_BOHR * (float)prod * phi * swt[e] * FAST_RCP(r));
}

extern "C" void kernel_launch(void* const* d_in, const int* in_sizes, int n_in,
                              void* d_out, int out_size, void* d_ws, size_t ws_size,
                              hipStream_t stream)
{
    const int*   species  = (const int*)  d_in[0];
    const int*   edge_src = (const int*)  d_in[1];
    const int*   edge_dst = (const int*)  d_in[2];
    const float* dist     = (const float*)d_in[3];
    const float* swt      = (const float*)d_in[4];
    const float* CS       = (const float*)d_in[5];
    const float* ALPHAS   = (const float*)d_in[6];
    float* out = (float*)d_out;

    int n_atoms = in_sizes[0];
    int n_edges = in_sizes[1];

    int nb = (n_atoms + APB - 1) / APB;
    long long capll = (long long)n_edges / nb + (long long)n_edges / ((long long)nb * 32) + 256;
    int cap = (int)((capll + 31) & ~31LL);
    int stride = nb * APB;

    size_t pairs_sz = ((size_t)nb * (size_t)cap * 4 + 255) & ~(size_t)255;
    size_t cur_sz   = ((size_t)nb * 4 + 255) & ~(size_t)255;
    size_t part_sz  = ((size_t)SPLITS * (size_t)stride * 4 + 255) & ~(size_t)255;
    size_t tab_sz   = ((size_t)NTAB * 16 + 255) & ~(size_t)255;
    size_t spc_sz   = ((size_t)n_atoms + 255) & ~(size_t)255;
    size_t s12_sz   = ((size_t)n_edges * 2 + 255) & ~(size_t)255;
    size_t need = pairs_sz + cur_sz + part_sz + tab_sz + spc_sz + s12_sz;

    if (nb <= NBMAX && n_edges > 0 && ws_size >= need) {
        char* w = (char*)d_ws;
        unsigned*       pairs   = (unsigned*)w;
        unsigned*       cursor  = (unsigned*)(w + pairs_sz);
        float*          partial = (float*)(w + pairs_sz + cur_sz);
        uint4*          tab16   = (uint4*)(w + pairs_sz + cur_sz + part_sz);
        unsigned char*  spc8    = (unsigned char*)(w + pairs_sz + cur_sz + part_sz + tab_sz);
        unsigned short* s12arr  = (unsigned short*)(w + pairs_sz + cur_sz + part_sz + tab_sz + spc_sz);

        int pmax = n_atoms > NTAB ? n_atoms : NTAB;
        p0_prep<<<(pmax + TPB - 1) / TPB, TPB, 0, stream>>>(
            CS, ALPHAS, species, tab16, spc8, cursor, n_atoms, nb);

        k1_s12<<<(n_edges + K1_BLK - 1) / K1_BLK, TPB, 0, stream>>>(
            edge_src, edge_dst, spc8, s12arr, n_edges);

        p1_bin<<<(n_edges + BLK_EDGES - 1) / BLK_EDGES, TPB, 0, stream>>>(
            edge_src, s12arr, dist, swt, tab16, pairs, cursor, nb, cap, n_edges);

        p2a_reduce<<<nb * SPLITS, TPB, 0, stream>>>(pairs, cursor, partial, cap, stride);
        p2b_sum<<<(n_atoms + TPB - 1) / TPB, TPB, 0, stream>>>(partial, out, n_atoms, stride);
    } else {
        (void)hipMemsetAsync(d_out, 0, (size_t)out_size * sizeof(float), stream);
        erep_edges_direct<<<(n_edges + TPB - 1) / TPB, TPB, 0, stream>>>(
            edge_src, edge_dst, dist, swt, species, CS, ALPHAS, out, n_edges);
    }
}

// Round 11
// 249.689 us; speedup vs baseline: 1.5468x; 1.0545x over previous
//
#include <hip/hip_runtime.h>
#include <hip/hip_fp16.h>

// RepulsionNLH: erep_atomic[a] = 0.5*BOHR * sum_{e: src[e]==a} Z[src]*Z[dst]*phi(e)*switch[e]/dist[e]
// phi(e) = sum_k CS[s12][k] * exp(-ALPHAS[s12][k] * dist[e]),  s12 = species[src] + 92*species[dst]
//
// R11: fuse k1 (species pre-gather) into p1 as a two-PHASE pipeline (not R8's
// two-LEVEL chain): phase A = all species gathers (16 in flight) + s12 + hist
// atomic + meta; scan/reserve; phase B = dist/swt streams + table gather +
// val -> stage[pos] directly. Drops the s12 38 MB round-trip, one dispatch,
// and the vals[]/src[] register buffers (VGPR ~70 vs R8's 128).

#define ZMAX_C 92
#define TAB93  93
#define NTAB   (TAB93 * TAB93)   // 8649
#define HALF_BOHR 0.264588605f   // 0.5 * 0.52917721
#define NBMAX 64
#define APB 2048                 // atoms per bucket
#define APB_LOG 11
#define SPLITS 16
#define TPB 256
#define EPT 16                   // edges per thread in p1
#define BLK_EDGES (TPB * EPT)    // 4096

typedef int            ivec4 __attribute__((ext_vector_type(4)));
typedef float          fvec4 __attribute__((ext_vector_type(4)));

#if __has_builtin(__builtin_amdgcn_rcpf)
#define FAST_RCP(x) __builtin_amdgcn_rcpf(x)
#else
#define FAST_RCP(x) (1.0f / (x))
#endif

// ---------------- p0: build Z-premult f16 table (93-stride), spc8, cursors --
__global__ __launch_bounds__(TPB) void p0_prep(
    const float* __restrict__ CS, const float* __restrict__ ALPHAS,
    const int* __restrict__ species,
    uint4* __restrict__ tab16, unsigned char* __restrict__ spc8,
    unsigned* __restrict__ cursor, int n_atoms, int nb)
{
    int i = blockIdx.x * TPB + threadIdx.x;
    if (i < NTAB) {
        int sd = i / TAB93;
        int ss = i - TAB93 * sd;
        int ref = ss + ZMAX_C * sd;          // reference's (colliding) index
        float Z = (ss > 0 && sd > 0) ? (float)(ss * sd) : 0.0f;
        __half h[8];
        h[0] = __float2half_rn(CS[3*ref+0] * Z);
        h[1] = __float2half_rn(CS[3*ref+1] * Z);
        h[2] = __float2half_rn(CS[3*ref+2] * Z);
        h[3] = __float2half_rn(-ALPHAS[3*ref+0]);
        h[4] = __float2half_rn(-ALPHAS[3*ref+1]);
        h[5] = __float2half_rn(-ALPHAS[3*ref+2]);
        h[6] = __half(0.0f); h[7] = __half(0.0f);
        tab16[i] = *reinterpret_cast<uint4*>(h);
    }
    if (i < n_atoms) spc8[i] = (unsigned char)species[i];
    if (i < nb) cursor[i] = 0u;
}

__device__ __forceinline__ float half_lo(unsigned u) {
    return __half2float(*reinterpret_cast<const __half*>(&u));
}
__device__ __forceinline__ float half_hi(unsigned u) {
    unsigned s = u >> 16;
    return __half2float(*reinterpret_cast<const __half*>(&s));
}

// ---------------- p1: fused species-gather + compute + bin ----------------
__global__ __launch_bounds__(TPB) void p1_bin(
    const int* __restrict__ edge_src, const int* __restrict__ edge_dst,
    const float* __restrict__ dist, const float* __restrict__ swt,
    const unsigned char* __restrict__ spc8, const uint4* __restrict__ tab16,
    unsigned* __restrict__ pairs, unsigned* __restrict__ cursor,
    int nb, int cap, int n_edges)
{
    __shared__ unsigned stage[BLK_EDGES];   // 16 KB: packed {lsrc<<16 | f16}
    __shared__ unsigned hist[NBMAX];
    __shared__ unsigned lbase[NBMAX];
    __shared__ unsigned gbase[NBMAX];

    int tid = threadIdx.x;
    if (tid < NBMAX) hist[tid] = 0;
    __syncthreads();

    int lane = tid & 63, wave = tid >> 6;
    long long wbase = (long long)blockIdx.x * BLK_EDGES + (long long)wave * (64 * EPT);

    unsigned meta[EPT];   // bit31 valid | rank<<17 | b<<11 | lsrc
    unsigned short s12r[EPT];

    // ---- phase A: stream src/dst, gather species (16 in flight), hist+meta --
    for (int jj = 0; jj < EPT / 8; ++jj) {
        long long eA = wbase + (jj*2+0) * 256 + lane * 4;
        long long eB = wbase + (jj*2+1) * 256 + lane * 4;
        int srcA[4], dstA[4], srcB[4], dstB[4];
        bool fullB = (eB + 3 < (long long)n_edges);
        if (fullB) {
            ivec4 s4 = __builtin_nontemporal_load((const ivec4*)(edge_src + eA));
            ivec4 d4 = __builtin_nontemporal_load((const ivec4*)(edge_dst + eA));
            ivec4 s5 = __builtin_nontemporal_load((const ivec4*)(edge_src + eB));
            ivec4 d5 = __builtin_nontemporal_load((const ivec4*)(edge_dst + eB));
            #pragma unroll
            for (int k = 0; k < 4; ++k) {
                srcA[k] = s4[k]; dstA[k] = d4[k];
                srcB[k] = s5[k]; dstB[k] = d5[k];
            }
        } else {
            #pragma unroll
            for (int k = 0; k < 4; ++k) {
                long long ea = eA + k, eb = eB + k;
                bool va = (ea < (long long)n_edges), vb = (eb < (long long)n_edges);
                srcA[k] = va ? edge_src[ea] : 0;  dstA[k] = va ? edge_dst[ea] : 0;
                srcB[k] = vb ? edge_src[eb] : 0;  dstB[k] = vb ? edge_dst[eb] : 0;
            }
        }
        // 16 species gathers in flight
        int ssA[4], sdA[4], ssB[4], sdB[4];
        #pragma unroll
        for (int k = 0; k < 4; ++k) { ssA[k] = spc8[srcA[k]]; sdA[k] = spc8[dstA[k]]; }
        #pragma unroll
        for (int k = 0; k < 4; ++k) { ssB[k] = spc8[srcB[k]]; sdB[k] = spc8[dstB[k]]; }
        // s12 + hist atomic + meta (overlaps next jj's gather latency)
        #pragma unroll
        for (int g = 0; g < 2; ++g) {
            const int* src = g ? srcB : srcA;
            const int* ss  = g ? ssB  : ssA;
            const int* sd  = g ? sdB  : sdA;
            long long  e0  = g ? eB   : eA;
            #pragma unroll
            for (int k = 0; k < 4; ++k) {
                int idx = jj * 8 + g * 4 + k;
                s12r[idx] = (unsigned short)(ss[k] + TAB93 * sd[k]);
                meta[idx] = 0u;
                if (e0 + k < (long long)n_edges) {
                    unsigned b    = (unsigned)src[k] >> APB_LOG;
                    unsigned lsrc = (unsigned)src[k] & (APB - 1);
                    unsigned rank = atomicAdd(&hist[b], 1u);   // < 4096
                    meta[idx] = 0x80000000u | (rank << 17) | (b << 11) | lsrc;
                }
            }
        }
    }
    __syncthreads();
    // wave-parallel exclusive scan of bucket counts (lanes 0..63 of wave 0)
    if (tid < 64) {
        unsigned v = (tid < nb) ? hist[tid] : 0u;
        unsigned x = v;
        #pragma unroll
        for (int off = 1; off < 64; off <<= 1) {
            unsigned y = __shfl_up(x, off);
            if ((tid & 63) >= off) x += y;
        }
        if (tid < nb) lbase[tid] = x - v;
    }
    __syncthreads();
    if (tid < nb) {
        unsigned c = hist[tid];
        gbase[tid] = c ? atomicAdd(cursor + tid, c) : 0u;
    }
    __syncthreads();

    // ---- phase B: stream dist/swt, table gather, compute, scatter to stage --
    for (int jj = 0; jj < EPT / 8; ++jj) {
        long long eA = wbase + (jj*2+0) * 256 + lane * 4;
        long long eB = wbase + (jj*2+1) * 256 + lane * 4;
        float rA[4], wA[4], rB[4], wB[4];
        bool fullB = (eB + 3 < (long long)n_edges);
        if (fullB) {
            fvec4 r4 = __builtin_nontemporal_load((const fvec4*)(dist + eA));
            fvec4 w4 = __builtin_nontemporal_load((const fvec4*)(swt + eA));
            fvec4 r5 = __builtin_nontemporal_load((const fvec4*)(dist + eB));
            fvec4 w5 = __builtin_nontemporal_load((const fvec4*)(swt + eB));
            #pragma unroll
            for (int k = 0; k < 4; ++k) {
                rA[k] = r4[k]; wA[k] = w4[k]; rB[k] = r5[k]; wB[k] = w5[k];
            }
        } else {
            #pragma unroll
            for (int k = 0; k < 4; ++k) {
                long long ea = eA + k, eb = eB + k;
                bool va = (ea < (long long)n_edges), vb = (eb < (long long)n_edges);
                rA[k] = va ? dist[ea] : 1.f;  wA[k] = va ? swt[ea] : 0.f;
                rB[k] = vb ? dist[eb] : 1.f;  wB[k] = vb ? swt[eb] : 0.f;
            }
        }
        // 8 table gathers in flight
        uint4 tA[4], tB[4];
        #pragma unroll
        for (int k = 0; k < 4; ++k) tA[k] = tab16[s12r[jj*8 + k]];
        #pragma unroll
        for (int k = 0; k < 4; ++k) tB[k] = tab16[s12r[jj*8 + 4 + k]];
        #pragma unroll
        for (int g = 0; g < 2; ++g) {
            const float* r = g ? rB : rA;
            const float* w = g ? wB : wA;
            const uint4* t = g ? tB : tA;
            #pragma unroll
            for (int k = 0; k < 4; ++k) {
                int idx = jj * 8 + g * 4 + k;
                unsigned m = meta[idx];
                if (!(m & 0x80000000u)) continue;
                float c0 = half_lo(t[k].x), c1 = half_hi(t[k].x);
                float c2 = half_lo(t[k].y), na0 = half_hi(t[k].y);
                float na1 = half_lo(t[k].z), na2 = half_hi(t[k].z);
                float phi = c0 * __expf(na0 * r[k])
                          + c1 * __expf(na1 * r[k])
                          + c2 * __expf(na2 * r[k]);
                float val = HALF_BOHR * phi * w[k] * FAST_RCP(r[k]);  // Z premult in c
                unsigned pos = lbase[(m >> 11) & 63u] + ((m >> 17) & 0x3FFFu);
                unsigned short hb = __half_as_ushort(__float2half_rn(val));
                stage[pos] = ((m & (APB - 1)) << 16) | (unsigned)hb;
            }
        }
    }
    __syncthreads();
    // coalesced copy-out, buckets distributed across the 4 waves
    for (int b = wave; b < nb; b += 4) {
        unsigned cnt = hist[b], lb = lbase[b], gb = gbase[b];
        unsigned* dst = pairs + (size_t)b * (size_t)cap + gb;
        for (unsigned i = lane; i < cnt; i += 64)
            if (gb + i < (unsigned)cap) dst[i] = stage[lb + i];
    }
}

// ---------------- p2a: per-bucket-slice LDS accumulation ----------------
__global__ __launch_bounds__(TPB) void p2a_reduce(
    const unsigned* __restrict__ pairs, const unsigned* __restrict__ cursor,
    float* __restrict__ partial, int cap, int stride)
{
    int b = blockIdx.x / SPLITS;
    int s = blockIdx.x % SPLITS;
    __shared__ float acc[APB];
    for (int i = threadIdx.x; i < APB; i += TPB) acc[i] = 0.f;
    __syncthreads();
    unsigned cnt = cursor[b];
    if (cnt > (unsigned)cap) cnt = (unsigned)cap;
    unsigned beg = (unsigned)((unsigned long long)cnt * s / SPLITS);
    unsigned end = (unsigned)((unsigned long long)cnt * (s + 1) / SPLITS);
    const unsigned* p = pairs + (size_t)b * (size_t)cap;
    unsigned i = beg + threadIdx.x;
    for (; i + 7u * TPB < end; i += 8u * TPB) {
        unsigned v[8];
        #pragma unroll
        for (int k = 0; k < 8; ++k) v[k] = p[i + (unsigned)k * TPB];
        #pragma unroll
        for (int k = 0; k < 8; ++k)
            unsafeAtomicAdd(&acc[v[k] >> 16],
                __half2float(__ushort_as_half((unsigned short)(v[k] & 0xFFFFu))));
    }
    for (; i < end; i += TPB) {
        unsigned v = p[i];
        unsafeAtomicAdd(&acc[v >> 16],
            __half2float(__ushort_as_half((unsigned short)(v & 0xFFFFu))));
    }
    __syncthreads();
    float* prow = partial + (size_t)s * stride + (size_t)b * APB;
    for (int k = threadIdx.x; k < APB; k += TPB) prow[k] = acc[k];
}

// ---------------- p2b: sum partials -> out ----------------
__global__ __launch_bounds__(TPB) void p2b_sum(
    const float* __restrict__ partial, float* __restrict__ out, int n, int stride)
{
    int i = blockIdx.x * TPB + threadIdx.x;
    if (i >= n) return;
    float s = 0.f;
    #pragma unroll
    for (int x = 0; x < SPLITS; ++x) s += partial[(size_t)x * stride + i];
    out[i] = s;
}

// ---------------- fallback: direct device atomics ----------------
__global__ __launch_bounds__(TPB) void erep_edges_direct(
    const int* __restrict__ edge_src, const int* __restrict__ edge_dst,
    const float* __restrict__ dist, const float* __restrict__ swt,
    const int* __restrict__ species, const float* __restrict__ CS,
    const float* __restrict__ ALPHAS, float* __restrict__ out, int n_edges)
{
    int e = blockIdx.x * TPB + threadIdx.x;
    if (e >= n_edges) return;
    int ss = species[edge_src[e]], sd = species[edge_dst[e]];
    int prod = ss * sd;
    if (prod == 0) return;
    int s12 = ss + ZMAX_C * sd;
    float r = dist[e];
    float phi = CS[3*s12+0] * __expf(-ALPHAS[3*s12+0] * r)
              + CS[3*s12+1] * __expf(-ALPHAS[3*s12+1] * r)
              + CS[3*s12+2] * __expf(-ALPHAS[3*s12+2] * r);
    atomicAdd(out + edge_src[e],
              HALF_BOHR * (float)prod * phi * swt[e] * FAST_RCP(r));
}

extern "C" void kernel_launch(void* const* d_in, const int* in_sizes, int n_in,
                              void* d_out, int out_size, void* d_ws, size_t ws_size,
                              hipStream_t stream)
{
    const int*   species  = (const int*)  d_in[0];
    const int*   edge_src = (const int*)  d_in[1];
    const int*   edge_dst = (const int*)  d_in[2];
    const float* dist     = (const float*)d_in[3];
    const float* swt      = (const float*)d_in[4];
    const float* CS       = (const float*)d_in[5];
    const float* ALPHAS   = (const float*)d_in[6];
    float* out = (float*)d_out;

    int n_atoms = in_sizes[0];
    int n_edges = in_sizes[1];

    int nb = (n_atoms + APB - 1) / APB;
    long long capll = (long long)n_edges / nb + (long long)n_edges / ((long long)nb * 32) + 256;
    int cap = (int)((capll + 31) & ~31LL);
    int stride = nb * APB;

    size_t pairs_sz = ((size_t)nb * (size_t)cap * 4 + 255) & ~(size_t)255;
    size_t cur_sz   = ((size_t)nb * 4 + 255) & ~(size_t)255;
    size_t part_sz  = ((size_t)SPLITS * (size_t)stride * 4 + 255) & ~(size_t)255;
    size_t tab_sz   = ((size_t)NTAB * 16 + 255) & ~(size_t)255;
    size_t spc_sz   = ((size_t)n_atoms + 255) & ~(size_t)255;
    size_t need = pairs_sz + cur_sz + part_sz + tab_sz + spc_sz;

    if (nb <= NBMAX && n_edges > 0 && ws_size >= need) {
        char* w = (char*)d_ws;
        unsigned*       pairs   = (unsigned*)w;
        unsigned*       cursor  = (unsigned*)(w + pairs_sz);
        float*          partial = (float*)(w + pairs_sz + cur_sz);
        uint4*          tab16   = (uint4*)(w + pairs_sz + cur_sz + part_sz);
        unsigned char*  spc8    = (unsigned char*)(w + pairs_sz + cur_sz + part_sz + tab_sz);

        int pmax = n_atoms > NTAB ? n_atoms : NTAB;
        p0_prep<<<(pmax + TPB - 1) / TPB, TPB, 0, stream>>>(
            CS, ALPHAS, species, tab16, spc8, cursor, n_atoms, nb);

        p1_bin<<<(n_edges + BLK_EDGES - 1) / BLK_EDGES, TPB, 0, stream>>>(
            edge_src, edge_dst, dist, swt, spc8, tab16,
            pairs, cursor, nb, cap, n_edges);

        p2a_reduce<<<nb * SPLITS, TPB, 0, stream>>>(pairs, cursor, partial, cap, stride);
        p2b_sum<<<(n_atoms + TPB - 1) / TPB, TPB, 0, stream>>>(partial, out, n_atoms, stride);
    } else {
        (void)hipMemsetAsync(d_out, 0, (size_t)out_size * sizeof(float), stream);
        erep_edges_direct<<<(n_edges + TPB - 1) / TPB, TPB, 0, stream>>>(
            edge_src, edge_dst, dist, swt, species, CS, ALPHAS, out, n_edges);
    }
}

// Round 12
// 249.033 us; speedup vs baseline: 1.5509x; 1.0026x over previous
//
#include <hip/hip_runtime.h>
#include <hip/hip_fp16.h>

// RepulsionNLH: erep_atomic[a] = 0.5*BOHR * sum_{e: src[e]==a} Z[src]*Z[dst]*phi(e)*switch[e]/dist[e]
// phi(e) = sum_k CS[s12][k] * exp(-ALPHAS[s12][k] * dist[e]),  s12 = species[src] + 92*species[dst]
//
// R12: (a) p1 hist atomics -> per-wave replicas hist4[4][64] (cross-wave
// same-address LDS-atomic serialization removed; rank is per-wave, folded
// back via per-wave bucket offsets at scatter). (b) phase A flattened: 16
// stream loads then 32 species gathers all in flight. (c) p2a uint4 pair
// loads (4 pairs/instr).

#define ZMAX_C 92
#define TAB93  93
#define NTAB   (TAB93 * TAB93)   // 8649
#define HALF_BOHR 0.264588605f   // 0.5 * 0.52917721
#define NBMAX 64
#define APB 2048                 // atoms per bucket
#define APB_LOG 11
#define SPLITS 16
#define TPB 256
#define EPT 16                   // edges per thread in p1
#define BLK_EDGES (TPB * EPT)    // 4096

typedef int            ivec4 __attribute__((ext_vector_type(4)));
typedef float          fvec4 __attribute__((ext_vector_type(4)));

#if __has_builtin(__builtin_amdgcn_rcpf)
#define FAST_RCP(x) __builtin_amdgcn_rcpf(x)
#else
#define FAST_RCP(x) (1.0f / (x))
#endif

// ---------------- p0: build Z-premult f16 table (93-stride), spc8, cursors --
__global__ __launch_bounds__(TPB) void p0_prep(
    const float* __restrict__ CS, const float* __restrict__ ALPHAS,
    const int* __restrict__ species,
    uint4* __restrict__ tab16, unsigned char* __restrict__ spc8,
    unsigned* __restrict__ cursor, int n_atoms, int nb)
{
    int i = blockIdx.x * TPB + threadIdx.x;
    if (i < NTAB) {
        int sd = i / TAB93;
        int ss = i - TAB93 * sd;
        int ref = ss + ZMAX_C * sd;          // reference's (colliding) index
        float Z = (ss > 0 && sd > 0) ? (float)(ss * sd) : 0.0f;
        __half h[8];
        h[0] = __float2half_rn(CS[3*ref+0] * Z);
        h[1] = __float2half_rn(CS[3*ref+1] * Z);
        h[2] = __float2half_rn(CS[3*ref+2] * Z);
        h[3] = __float2half_rn(-ALPHAS[3*ref+0]);
        h[4] = __float2half_rn(-ALPHAS[3*ref+1]);
        h[5] = __float2half_rn(-ALPHAS[3*ref+2]);
        h[6] = __half(0.0f); h[7] = __half(0.0f);
        tab16[i] = *reinterpret_cast<uint4*>(h);
    }
    if (i < n_atoms) spc8[i] = (unsigned char)species[i];
    if (i < nb) cursor[i] = 0u;
}

__device__ __forceinline__ float half_lo(unsigned u) {
    return __half2float(*reinterpret_cast<const __half*>(&u));
}
__device__ __forceinline__ float half_hi(unsigned u) {
    unsigned s = u >> 16;
    return __half2float(*reinterpret_cast<const __half*>(&s));
}

// ---------------- p1: fused species-gather + compute + bin ----------------
__global__ __launch_bounds__(TPB) void p1_bin(
    const int* __restrict__ edge_src, const int* __restrict__ edge_dst,
    const float* __restrict__ dist, const float* __restrict__ swt,
    const unsigned char* __restrict__ spc8, const uint4* __restrict__ tab16,
    unsigned* __restrict__ pairs, unsigned* __restrict__ cursor,
    int nb, int cap, int n_edges)
{
    __shared__ unsigned stage[BLK_EDGES];   // 16 KB: packed {lsrc<<16 | f16}
    __shared__ unsigned hist4[4][NBMAX];    // per-wave histogram replicas
    __shared__ unsigned hist[NBMAX];        // bucket totals
    __shared__ unsigned lbase[NBMAX];
    __shared__ unsigned gbase[NBMAX];

    int tid = threadIdx.x;
    if (tid < NBMAX) {
        hist4[0][tid] = 0; hist4[1][tid] = 0;
        hist4[2][tid] = 0; hist4[3][tid] = 0;
    }
    __syncthreads();

    int lane = tid & 63, wave = tid >> 6;
    long long wbase = (long long)blockIdx.x * BLK_EDGES + (long long)wave * (64 * EPT);

    unsigned meta[EPT];   // bit31 valid | rank<<17 | b<<11 | lsrc  (rank per-wave)
    unsigned short s12r[EPT];

    // ---- phase A: all stream loads, then all 32 species gathers in flight --
    {
        int srcv[EPT], dstv[EPT];
        #pragma unroll
        for (int j = 0; j < EPT / 4; ++j) {
            long long e0 = wbase + j * 256 + lane * 4;
            if (e0 + 3 < (long long)n_edges) {
                ivec4 s4 = __builtin_nontemporal_load((const ivec4*)(edge_src + e0));
                ivec4 d4 = __builtin_nontemporal_load((const ivec4*)(edge_dst + e0));
                #pragma unroll
                for (int k = 0; k < 4; ++k) { srcv[j*4+k] = s4[k]; dstv[j*4+k] = d4[k]; }
            } else {
                #pragma unroll
                for (int k = 0; k < 4; ++k) {
                    long long e = e0 + k;
                    bool v = (e < (long long)n_edges);
                    srcv[j*4+k] = v ? edge_src[e] : 0;
                    dstv[j*4+k] = v ? edge_dst[e] : 0;
                }
            }
        }
        int ssv[EPT], sdv[EPT];
        #pragma unroll
        for (int i = 0; i < EPT; ++i) ssv[i] = spc8[srcv[i]];
        #pragma unroll
        for (int i = 0; i < EPT; ++i) sdv[i] = spc8[dstv[i]];
        #pragma unroll
        for (int j = 0; j < EPT / 4; ++j) {
            long long e0 = wbase + j * 256 + lane * 4;
            #pragma unroll
            for (int k = 0; k < 4; ++k) {
                int idx = j * 4 + k;
                s12r[idx] = (unsigned short)(ssv[idx] + TAB93 * sdv[idx]);
                meta[idx] = 0u;
                if (e0 + k < (long long)n_edges) {
                    unsigned b    = (unsigned)srcv[idx] >> APB_LOG;
                    unsigned lsrc = (unsigned)srcv[idx] & (APB - 1);
                    unsigned rank = atomicAdd(&hist4[wave][b], 1u);   // < 1024
                    meta[idx] = 0x80000000u | (rank << 17) | (b << 11) | lsrc;
                }
            }
        }
    }
    __syncthreads();
    // fold wave replicas into totals + per-wave offsets; scan; reserve
    if (tid < 64) {
        unsigned h0 = hist4[0][tid], h1 = hist4[1][tid];
        unsigned h2 = hist4[2][tid], h3 = hist4[3][tid];
        unsigned tot = h0 + h1 + h2 + h3;
        hist4[0][tid] = 0;
        hist4[1][tid] = h0;
        hist4[2][tid] = h0 + h1;
        hist4[3][tid] = h0 + h1 + h2;
        if (tid < nb) hist[tid] = tot;
        // wave-parallel exclusive scan of tot over 64 lanes
        unsigned v = (tid < nb) ? tot : 0u;
        unsigned x = v;
        #pragma unroll
        for (int off = 1; off < 64; off <<= 1) {
            unsigned y = __shfl_up(x, off);
            if ((tid & 63) >= off) x += y;
        }
        if (tid < nb) {
            lbase[tid] = x - v;
            gbase[tid] = v ? atomicAdd(cursor + tid, v) : 0u;
        }
    }
    __syncthreads();

    // ---- phase B: stream dist/swt, table gather, compute, scatter to stage --
    for (int jj = 0; jj < EPT / 8; ++jj) {
        long long eA = wbase + (jj*2+0) * 256 + lane * 4;
        long long eB = wbase + (jj*2+1) * 256 + lane * 4;
        float rA[4], wA[4], rB[4], wB[4];
        bool fullB = (eB + 3 < (long long)n_edges);
        if (fullB) {
            fvec4 r4 = __builtin_nontemporal_load((const fvec4*)(dist + eA));
            fvec4 w4 = __builtin_nontemporal_load((const fvec4*)(swt + eA));
            fvec4 r5 = __builtin_nontemporal_load((const fvec4*)(dist + eB));
            fvec4 w5 = __builtin_nontemporal_load((const fvec4*)(swt + eB));
            #pragma unroll
            for (int k = 0; k < 4; ++k) {
                rA[k] = r4[k]; wA[k] = w4[k]; rB[k] = r5[k]; wB[k] = w5[k];
            }
        } else {
            #pragma unroll
            for (int k = 0; k < 4; ++k) {
                long long ea = eA + k, eb = eB + k;
                bool va = (ea < (long long)n_edges), vb = (eb < (long long)n_edges);
                rA[k] = va ? dist[ea] : 1.f;  wA[k] = va ? swt[ea] : 0.f;
                rB[k] = vb ? dist[eb] : 1.f;  wB[k] = vb ? swt[eb] : 0.f;
            }
        }
        // 8 table gathers in flight
        uint4 tA[4], tB[4];
        #pragma unroll
        for (int k = 0; k < 4; ++k) tA[k] = tab16[s12r[jj*8 + k]];
        #pragma unroll
        for (int k = 0; k < 4; ++k) tB[k] = tab16[s12r[jj*8 + 4 + k]];
        #pragma unroll
        for (int g = 0; g < 2; ++g) {
            const float* r = g ? rB : rA;
            const float* w = g ? wB : wA;
            const uint4* t = g ? tB : tA;
            #pragma unroll
            for (int k = 0; k < 4; ++k) {
                int idx = jj * 8 + g * 4 + k;
                unsigned m = meta[idx];
                if (!(m & 0x80000000u)) continue;
                float c0 = half_lo(t[k].x), c1 = half_hi(t[k].x);
                float c2 = half_lo(t[k].y), na0 = half_hi(t[k].y);
                float na1 = half_lo(t[k].z), na2 = half_hi(t[k].z);
                float phi = c0 * __expf(na0 * r[k])
                          + c1 * __expf(na1 * r[k])
                          + c2 * __expf(na2 * r[k]);
                float val = HALF_BOHR * phi * w[k] * FAST_RCP(r[k]);  // Z premult in c
                unsigned b = (m >> 11) & 63u;
                unsigned pos = lbase[b] + hist4[wave][b] + ((m >> 17) & 0x3FFFu);
                unsigned short hb = __half_as_ushort(__float2half_rn(val));
                stage[pos] = ((m & (APB - 1)) << 16) | (unsigned)hb;
            }
        }
    }
    __syncthreads();
    // coalesced copy-out, buckets distributed across the 4 waves
    for (int b = wave; b < nb; b += 4) {
        unsigned cnt = hist[b], lb = lbase[b], gb = gbase[b];
        unsigned* dst = pairs + (size_t)b * (size_t)cap + gb;
        for (unsigned i = lane; i < cnt; i += 64)
            if (gb + i < (unsigned)cap) dst[i] = stage[lb + i];
    }
}

// ---------------- p2a: per-bucket-slice LDS accumulation ----------------
__global__ __launch_bounds__(TPB) void p2a_reduce(
    const unsigned* __restrict__ pairs, const unsigned* __restrict__ cursor,
    float* __restrict__ partial, int cap, int stride)
{
    int b = blockIdx.x / SPLITS;
    int s = blockIdx.x % SPLITS;
    __shared__ float acc[APB];
    for (int i = threadIdx.x; i < APB; i += TPB) acc[i] = 0.f;
    __syncthreads();
    unsigned cnt = cursor[b];
    if (cnt > (unsigned)cap) cnt = (unsigned)cap;
    unsigned nq = (cnt + 3u) >> 2;                       // pair-quads
    unsigned qb = (unsigned)((unsigned long long)nq * s / SPLITS);
    unsigned qe = (unsigned)((unsigned long long)nq * (s + 1) / SPLITS);
    const uint4* p4 = (const uint4*)(pairs + (size_t)b * (size_t)cap);
    for (unsigned q = qb + threadIdx.x; q < qe; q += TPB) {
        uint4 v = p4[q];
        unsigned base = q << 2;
        if (base + 3u < cnt) {
            unsafeAtomicAdd(&acc[v.x >> 16], __half2float(__ushort_as_half((unsigned short)(v.x & 0xFFFFu))));
            unsafeAtomicAdd(&acc[v.y >> 16], __half2float(__ushort_as_half((unsigned short)(v.y & 0xFFFFu))));
            unsafeAtomicAdd(&acc[v.z >> 16], __half2float(__ushort_as_half((unsigned short)(v.z & 0xFFFFu))));
            unsafeAtomicAdd(&acc[v.w >> 16], __half2float(__ushort_as_half((unsigned short)(v.w & 0xFFFFu))));
        } else {
            unsigned vv[4] = {v.x, v.y, v.z, v.w};
            #pragma unroll
            for (int e = 0; e < 4; ++e)
                if (base + (unsigned)e < cnt)
                    unsafeAtomicAdd(&acc[vv[e] >> 16],
                        __half2float(__ushort_as_half((unsigned short)(vv[e] & 0xFFFFu))));
        }
    }
    __syncthreads();
    float* prow = partial + (size_t)s * stride + (size_t)b * APB;
    for (int k = threadIdx.x; k < APB; k += TPB) prow[k] = acc[k];
}

// ---------------- p2b: sum partials -> out ----------------
__global__ __launch_bounds__(TPB) void p2b_sum(
    const float* __restrict__ partial, float* __restrict__ out, int n, int stride)
{
    int i = blockIdx.x * TPB + threadIdx.x;
    if (i >= n) return;
    float s = 0.f;
    #pragma unroll
    for (int x = 0; x < SPLITS; ++x) s += partial[(size_t)x * stride + i];
    out[i] = s;
}

// ---------------- fallback: direct device atomics ----------------
__global__ __launch_bounds__(TPB) void erep_edges_direct(
    const int* __restrict__ edge_src, const int* __restrict__ edge_dst,
    const float* __restrict__ dist, const float* __restrict__ swt,
    const int* __restrict__ species, const float* __restrict__ CS,
    const float* __restrict__ ALPHAS, float* __restrict__ out, int n_edges)
{
    int e = blockIdx.x * TPB + threadIdx.x;
    if (e >= n_edges) return;
    int ss = species[edge_src[e]], sd = species[edge_dst[e]];
    int prod = ss * sd;
    if (prod == 0) return;
    int s12 = ss + ZMAX_C * sd;
    float r = dist[e];
    float phi = CS[3*s12+0] * __expf(-ALPHAS[3*s12+0] * r)
              + CS[3*s12+1] * __expf(-ALPHAS[3*s12+1] * r)
              + CS[3*s12+2] * __expf(-ALPHAS[3*s12+2] * r);
    atomicAdd(out + edge_src[e],
              HALF_BOHR * (float)prod * phi * swt[e] * FAST_RCP(r));
}

extern "C" void kernel_launch(void* const* d_in, const int* in_sizes, int n_in,
                              void* d_out, int out_size, void* d_ws, size_t ws_size,
                              hipStream_t stream)
{
    const int*   species  = (const int*)  d_in[0];
    const int*   edge_src = (const int*)  d_in[1];
    const int*   edge_dst = (const int*)  d_in[2];
    const float* dist     = (const float*)d_in[3];
    const float* swt      = (const float*)d_in[4];
    const float* CS       = (const float*)d_in[5];
    const float* ALPHAS   = (const float*)d_in[6];
    float* out = (float*)d_out;

    int n_atoms = in_sizes[0];
    int n_edges = in_sizes[1];

    int nb = (n_atoms + APB - 1) / APB;
    long long capll = (long long)n_edges / nb + (long long)n_edges / ((long long)nb * 32) + 256;
    int cap = (int)((capll + 31) & ~31LL);
    int stride = nb * APB;

    size_t pairs_sz = ((size_t)nb * (size_t)cap * 4 + 255) & ~(size_t)255;
    size_t cur_sz   = ((size_t)nb * 4 + 255) & ~(size_t)255;
    size_t part_sz  = ((size_t)SPLITS * (size_t)stride * 4 + 255) & ~(size_t)255;
    size_t tab_sz   = ((size_t)NTAB * 16 + 255) & ~(size_t)255;
    size_t spc_sz   = ((size_t)n_atoms + 255) & ~(size_t)255;
    size_t need = pairs_sz + cur_sz + part_sz + tab_sz + spc_sz;

    if (nb <= NBMAX && n_edges > 0 && ws_size >= need) {
        char* w = (char*)d_ws;
        unsigned*       pairs   = (unsigned*)w;
        unsigned*       cursor  = (unsigned*)(w + pairs_sz);
        float*          partial = (float*)(w + pairs_sz + cur_sz);
        uint4*          tab16   = (uint4*)(w + pairs_sz + cur_sz + part_sz);
        unsigned char*  spc8    = (unsigned char*)(w + pairs_sz + cur_sz + part_sz + tab_sz);

        int pmax = n_atoms > NTAB ? n_atoms : NTAB;
        p0_prep<<<(pmax + TPB - 1) / TPB, TPB, 0, stream>>>(
            CS, ALPHAS, species, tab16, spc8, cursor, n_atoms, nb);

        p1_bin<<<(n_edges + BLK_EDGES - 1) / BLK_EDGES, TPB, 0, stream>>>(
            edge_src, edge_dst, dist, swt, spc8, tab16,
            pairs, cursor, nb, cap, n_edges);

        p2a_reduce<<<nb * SPLITS, TPB, 0, stream>>>(pairs, cursor, partial, cap, stride);
        p2b_sum<<<(n_atoms + TPB - 1) / TPB, TPB, 0, stream>>>(partial, out, n_atoms, stride);
    } else {
        (void)hipMemsetAsync(d_out, 0, (size_t)out_size * sizeof(float), stream);
        erep_edges_direct<<<(n_edges + TPB - 1) / TPB, TPB, 0, stream>>>(
            edge_src, edge_dst, dist, swt, species, CS, ALPHAS, out, n_edges);
    }
}